// Round 11
// baseline (33.765 us; speedup 1.0000x reference)
//
#include <hip/hip_runtime.h>
#include <math.h>

// Problem dims (fixed)
#define NN      16
#define WIDTH   64
#define TT      2048
#define NBINS   2048
#define NROWS   32768      // NN*TT
#define NELEM   2097152    // NN*WIDTH*TT
#define NBLK_VQ 512        // 64 rows per block, all 2048 bins

typedef unsigned short u16;
typedef unsigned int   u32;
typedef __attribute__((ext_vector_type(8))) short short8;   // 8 bf16 (4 VGPRs)
typedef __attribute__((ext_vector_type(4))) float f32x4;

#define MFMA_BF16 __builtin_amdgcn_mfma_f32_16x16x32_bf16
#define KEYMASK   0xFFFFF800u
// DBIAS must exceed max|2*dot(x,cb)| so the discriminant is ALWAYS > 0
// (u32 float-ordering breaks for negatives). |dot| sigma ~0.031 -> 0.5 = 16σ.
#define DBIAS     0.5f

__device__ __forceinline__ u16 f2bf(float f) {            // RNE f32 -> bf16 bits
    u32 u = __float_as_uint(f);
    u32 r = u + 0x7FFFu + ((u >> 16) & 1u);
    return (u16)(r >> 16);
}

// ---------------------------------------------------------------------------
// Prep: cbT = bf16(cb) in MFMA-tiled layout; cbnC = ||cb||^2 + DBIAS.
// Also zeroes the two scalar outputs (loss/fit accumulators).
// cbT chunk layout: [bin16][kc][kseg][col][8elem]; k = kc*32 + kseg*8 + i.
// ---------------------------------------------------------------------------
__global__ __launch_bounds__(256) void cbprep_k(const float* __restrict__ cb,
                                                u16* __restrict__ cbT,
                                                float* __restrict__ cbnC,
                                                float* __restrict__ out) {
    int g = blockIdx.x * 256 + threadIdx.x;    // grid 32 -> 8192 threads
    if (g == 0) { out[NELEM] = 0.f; out[NELEM + 1] = 0.f; }
    int b = g >> 2, q = g & 3;                 // bin, quarter (16 k each)
    const float4* p = (const float4*)(cb + (size_t)b * 64) + q * 4;
    const int base = (b >> 4) * 1024 + (b & 15) * 8;
    float s = 0.f;
#pragma unroll
    for (int c = 0; c < 2; ++c) {              // octet o = q*2 + c
        float4 v0 = p[c * 2], v1 = p[c * 2 + 1];
        s += v0.x * v0.x + v0.y * v0.y + v0.z * v0.z + v0.w * v0.w;
        s += v1.x * v1.x + v1.y * v1.y + v1.z * v1.z + v1.w * v1.w;
        short8 h = { (short)f2bf(v0.x), (short)f2bf(v0.y), (short)f2bf(v0.z),
                     (short)f2bf(v0.w), (short)f2bf(v1.x), (short)f2bf(v1.y),
                     (short)f2bf(v1.z), (short)f2bf(v1.w) };
        int o = q * 2 + c;
        *(short8*)&cbT[base + (o >> 2) * 512 + (o & 3) * 128] = h;
    }
    s += __shfl_xor(s, 1, 64);
    s += __shfl_xor(s, 2, 64);
    if (q == 0) cbnC[b] = s + DBIAS;
}

// ---------------------------------------------------------------------------
// Main (r4-proven 25.3us structure): block = 64 rows x ALL 2048 bins
// (16 tiles of 128). 256 threads = 4 waves; wave bg owns a 32-bin slice of
// each tile (2x16 sub-slices), all 64 rows. B streamed from L2 via 2-deep
// NAMED register double-buffer, 4 short8 per PF (chunky MLP). Argmin via
// sortable u32 keys: d = cbnC[b] - 2*dot > 0 (DBIAS=0.5 fix),
// key = (bits(d)&~0x7FF)|bin. launch_bounds(256,2): 8 waves/CU, 256-VGPR
// budget -- r4-proven. Fused epilogue: raw-view gather + STE + loss/fit,
// scalars atomicAdd'ed pre-scaled into out[NELEM..+1]. 2 dispatches total.
// ---------------------------------------------------------------------------
__global__ __launch_bounds__(256, 2) void vq_main_k(
    const float* __restrict__ x, const u16* __restrict__ cbT,
    const float* __restrict__ cbnC, const float* __restrict__ cb,
    float* __restrict__ out) {
    // A: [t][k] bf16, 64x64, XOR-swizzled: elem = t*64 + (k ^ ((t&7)<<3))
    __shared__ __align__(16) u16 Ah[64 * 64];
    __shared__ float xnp[4][64];
    __shared__ float xnorm_s[64];
    __shared__ u32   kq_s[4][64];
    __shared__ int   bi_m[64];
    __shared__ float red_l[4];
    __shared__ float red_f;

    const int tid  = threadIdx.x;
    const int lane = tid & 63;
    const int bg   = tid >> 6;      // wave 0..3 = bin sub-slice
    const int col  = lane & 15;
    const int kseg = lane >> 4;     // 0..3

    const int r0 = blockIdx.x * 64;   // rows r0..r0+63; row = n*2048 + t
    const int n  = r0 >> 11;
    const int t0 = r0 & 2047;

    // ---- Stage A: x fp32 -> bf16 [t][k] swizzled; exact fp32 xnorm ----
    {
        const int t  = tid & 63;
        const int kb = tid >> 6;     // 0..3
        const float* xp = x + (size_t)n * (WIDTH * TT) + t0 + t;
        const int sw = (t & 7) << 3;
        float xs = 0.f;
#pragma unroll
        for (int it = 0; it < 8; ++it) {
            int k2 = kb * 16 + it * 2;
            float v0 = xp[(size_t)k2 * TT];
            float v1 = xp[(size_t)(k2 + 1) * TT];
            xs += v0 * v0 + v1 * v1;
            u32 pack = (u32)f2bf(v0) | ((u32)f2bf(v1) << 16);
            *(u32*)&Ah[t * 64 + (k2 ^ sw)] = pack;   // k2 even -> pair intact
        }
        xnp[kb][t] = xs;
    }
    __syncthreads();
    if (tid < 64)
        xnorm_s[tid] = xnp[0][tid] + xnp[1][tid] + xnp[2][tid] + xnp[3][tid];

    // ---- A fragments in registers (held across all 16 tiles) ----
    short8 afh[4][2];
#pragma unroll
    for (int rs = 0; rs < 4; ++rs) {
        const int rt = rs * 16 + col;
        const int sw = (rt & 7) << 3;
#pragma unroll
        for (int kc = 0; kc < 2; ++kc)
            afh[rs][kc] = *(const short8*)&Ah[rt * 64 + ((kc * 32 + kseg * 8) ^ sw)];
    }

    u32 keys[16];
#pragma unroll
    for (int i = 0; i < 16; ++i) keys[i] = 0xFFFFFFFFu;

    const int fragoff = kseg * 128 + col * 8;   // within a 1KB cbT chunk

    // Named double-buffer register sets (NO runtime indexing anywhere).
    short8 bA00, bA01, bA10, bA11, bB00, bB01, bB10, bB11;
    float  cnA0, cnA1, cnB0, cnB1;

#define PREFETCH(S00, S01, S10, S11, C0, C1, TILE) do {                       \
        const int _bb = (TILE) * 128 + bg * 32 + col;                         \
        const int _c16 = ((TILE) * 8 + bg * 2) * 1024 + fragoff;              \
        C0 = cbnC[_bb];  C1 = cbnC[_bb + 16];                                 \
        S00 = *(const short8*)&cbT[_c16];                                     \
        S01 = *(const short8*)&cbT[_c16 + 512];                               \
        S10 = *(const short8*)&cbT[_c16 + 1024];                              \
        S11 = *(const short8*)&cbT[_c16 + 1536];                              \
    } while (0)

#define COMPUTE(S00, S01, S10, S11, C0, C1, TILE) do {                        \
        const u32 bin0 = (u32)((TILE) * 128 + bg * 32 + col);                 \
        const u32 bin1 = bin0 + 16;                                           \
        _Pragma("unroll")                                                     \
        for (int rs = 0; rs < 4; ++rs) {                                      \
            f32x4 a0 = {0.f, 0.f, 0.f, 0.f}, a1 = {0.f, 0.f, 0.f, 0.f};      \
            a0 = MFMA_BF16(afh[rs][0], S00, a0, 0, 0, 0);                     \
            a0 = MFMA_BF16(afh[rs][1], S01, a0, 0, 0, 0);                     \
            a1 = MFMA_BF16(afh[rs][0], S10, a1, 0, 0, 0);                     \
            a1 = MFMA_BF16(afh[rs][1], S11, a1, 0, 0, 0);                     \
            _Pragma("unroll")                                                 \
            for (int jj = 0; jj < 4; ++jj) {                                  \
                float d0 = fmaf(-2.f, a0[jj], C0);                            \
                float d1 = fmaf(-2.f, a1[jj], C1);                            \
                u32 k0 = (__float_as_uint(d0) & KEYMASK) | bin0;              \
                u32 k1 = (__float_as_uint(d1) & KEYMASK) | bin1;              \
                u32 km = k0 < k1 ? k0 : k1;                                   \
                int li = rs * 4 + jj;                                         \
                keys[li] = km < keys[li] ? km : keys[li];                     \
            }                                                                 \
        }                                                                     \
    } while (0)

    PREFETCH(bA00, bA01, bA10, bA11, cnA0, cnA1, 0);
#pragma unroll
    for (int tp = 0; tp < 8; ++tp) {
        const int t1_ = tp * 2 + 1;
        const int t2_ = (tp * 2 + 2) & 15;     // wraps: harmless extra prefetch
        PREFETCH(bB00, bB01, bB10, bB11, cnB0, cnB1, t1_);
        COMPUTE(bA00, bA01, bA10, bA11, cnA0, cnA1, tp * 2);
        PREFETCH(bA00, bA01, bA10, bA11, cnA0, cnA1, t2_);
        COMPUTE(bB00, bB01, bB10, bB11, cnB0, cnB1, t1_);
    }
#undef PREFETCH
#undef COMPUTE

    // ---- issue epilogue x-read now (hides HBM latency under reduction) ----
    const size_t ob = (size_t)r0 * 64 + (size_t)tid * 16;
    float4 xv0 = *(const float4*)(x + ob);
    float4 xv1 = *(const float4*)(x + ob + 4);
    float4 xv2 = *(const float4*)(x + ob + 8);
    float4 xv3 = *(const float4*)(x + ob + 12);

    // ---- reduce across 16 col-lanes (u32 min = value then lowest bin) ----
#pragma unroll
    for (int m = 1; m <= 8; m <<= 1) {
#pragma unroll
        for (int i = 0; i < 16; ++i) {
            u32 ok = (u32)__shfl_xor((int)keys[i], m, 64);
            keys[i] = ok < keys[i] ? ok : keys[i];
        }
    }
    if (col == 0) {
#pragma unroll
        for (int rs = 0; rs < 4; ++rs)
#pragma unroll
            for (int jj = 0; jj < 4; ++jj)
                kq_s[bg][rs * 16 + kseg * 4 + jj] = keys[rs * 4 + jj];
    }
    __syncthreads();

    // ---- cross-wave merge + fit partial (wave 0) ----
    if (tid < 64) {
        u32 k0 = kq_s[0][tid], k1 = kq_s[1][tid];
        u32 k2 = kq_s[2][tid], k3 = kq_s[3][tid];
        u32 ka = k0 < k1 ? k0 : k1;
        u32 kb2 = k2 < k3 ? k2 : k3;
        u32 km = ka < kb2 ? ka : kb2;
        bi_m[tid] = (int)(km & 0x7FFu);
        float d = __uint_as_float(km & KEYMASK) - DBIAS;
        float fv = sqrtf(fmaxf(xnorm_s[tid] + d, 0.f));
#pragma unroll
        for (int m = 32; m >= 1; m >>= 1) fv += __shfl_xor(fv, m, 64);
        if (tid == 0) red_f = fv;
    }
    __syncthreads();

    // ---- fused epilogue: raw-view gather + STE write + loss partial ----
    const int rl = tid >> 2;                 // local row 0..63
    const int id = bi_m[rl];
    const float* qrow = cb + (size_t)id * 64 + (tid & 3) * 16;
    float4 q0 = *(const float4*)(qrow);
    float4 q1 = *(const float4*)(qrow + 4);
    float4 q2 = *(const float4*)(qrow + 8);
    float4 q3 = *(const float4*)(qrow + 12);
    float ls = 0.f;
#define STE(QV, XV, OFF) do {                                                 \
        float4 qo;                                                            \
        qo.x = XV.x + (QV.x - XV.x); qo.y = XV.y + (QV.y - XV.y);             \
        qo.z = XV.z + (QV.z - XV.z); qo.w = XV.w + (QV.w - XV.w);             \
        *(float4*)(out + ob + OFF) = qo;                                      \
        float dx = QV.x - XV.x, dy = QV.y - XV.y;                             \
        float dz = QV.z - XV.z, dw = QV.w - XV.w;                             \
        ls += dx * dx + dy * dy + dz * dz + dw * dw;                          \
    } while (0)
    STE(q0, xv0, 0); STE(q1, xv1, 4); STE(q2, xv2, 8); STE(q3, xv3, 12);
#undef STE
#pragma unroll
    for (int m = 32; m >= 1; m >>= 1) ls += __shfl_xor(ls, m, 64);
    if (lane == 0) red_l[bg] = ls;
    __syncthreads();
    if (tid == 0) {
        float lsum = red_l[0] + red_l[1] + red_l[2] + red_l[3];
        // loss = codebook_loss + 0.25*commit_loss = 1.25 * mean((q-x)^2)
        atomicAdd(out + NELEM,     1.25f * lsum / (float)NELEM);
        atomicAdd(out + NELEM + 1, red_f / (float)NROWS);
    }
}

// ---------------------------------------------------------------------------
extern "C" void kernel_launch(void* const* d_in, const int* in_sizes, int n_in,
                              void* d_out, int out_size, void* d_ws, size_t ws_size,
                              hipStream_t stream) {
    const float* x  = (const float*)d_in[0];   // (16,64,2048) fp32
    const float* cb = (const float*)d_in[1];   // (2048,64) fp32
    float* out = (float*)d_out;                // [2097152 quantized][loss][fit]

    char* ws = (char*)d_ws;
    float* cbnC = (float*)(ws);                // 8 KB
    u16*   cbT  = (u16*)  (ws + 8192);         // 256 KB

    cbprep_k<<<32,       256, 0, stream>>>(cb, cbT, cbnC, out);
    vq_main_k<<<NBLK_VQ, 256, 0, stream>>>(x, cbT, cbnC, cb, out);
}

// Round 12
// 25.221 us; speedup vs baseline: 1.3388x; 1.3388x over previous
//
#include <hip/hip_runtime.h>
#include <math.h>

// Problem dims (fixed)
#define NN      16
#define WIDTH   64
#define TT      2048
#define NBINS   2048
#define NROWS   32768      // NN*TT
#define NELEM   2097152    // NN*WIDTH*TT
#define NBLK_VQ 512        // 64 rows per block, all 2048 bins

typedef unsigned short u16;
typedef unsigned int   u32;
typedef __attribute__((ext_vector_type(8))) short short8;   // 8 bf16 (4 VGPRs)
typedef __attribute__((ext_vector_type(4))) float f32x4;

#define MFMA_BF16 __builtin_amdgcn_mfma_f32_16x16x32_bf16
#define KEYMASK   0xFFFFF800u
// DBIAS must exceed max|2*dot(x,cb)| so the discriminant is ALWAYS > 0
// (u32 float-ordering breaks for negatives). |dot| sigma ~0.031 -> 0.5 = 16σ.
#define DBIAS     0.5f

__device__ __forceinline__ u16 f2bf(float f) {            // RNE f32 -> bf16 bits
    u32 u = __float_as_uint(f);
    u32 r = u + 0x7FFFu + ((u >> 16) & 1u);
    return (u16)(r >> 16);
}

// ---------------------------------------------------------------------------
// Prep: codebook -> bf16 in MFMA-tiled layout cbT + biased norms cbnC.
// cbT chunk layout: [bin16][kc][kseg][col][8elem] ; bin=bin16*16+col,
// k = kc*32 + kseg*8 + i  -> a wave's B-fragment load is 1KB contiguous.
// ---------------------------------------------------------------------------
__global__ __launch_bounds__(256) void cbprep_k(const float* __restrict__ cb,
                                                u16* __restrict__ cbT,
                                                float* __restrict__ cbnC) {
    int b = blockIdx.x * 256 + threadIdx.x;   // grid 8 -> 2048 bins
    const float4* p = (const float4*)(cb + (size_t)b * 64);
    float s = 0.f;
    const int base = (b >> 4) * 1024 + (b & 15) * 8;
#pragma unroll
    for (int o = 0; o < 8; ++o) {             // k-octet: kc=o>>2, kseg=o&3
        float4 v0 = p[o * 2], v1 = p[o * 2 + 1];
        s += v0.x * v0.x + v0.y * v0.y + v0.z * v0.z + v0.w * v0.w;
        s += v1.x * v1.x + v1.y * v1.y + v1.z * v1.z + v1.w * v1.w;
        short8 h = { (short)f2bf(v0.x), (short)f2bf(v0.y), (short)f2bf(v0.z),
                     (short)f2bf(v0.w), (short)f2bf(v1.x), (short)f2bf(v1.y),
                     (short)f2bf(v1.z), (short)f2bf(v1.w) };
        *(short8*)&cbT[base + (o >> 2) * 512 + (o & 3) * 128] = h;
    }
    cbnC[b] = s + DBIAS;
}

// ---------------------------------------------------------------------------
// Main: block = 64 rows x all 2048 bins. 256 threads = 4 waves, wave = bin
// slice bg (32 bins of each 128-bin tile), all 64 rows (4 MFMA row-tiles).
// B streamed from L2 via named register double-buffer (no runtime indexing,
// no barriers in the 16-tile loop). Argmin via sortable u32 keys:
//   d = cbnC[b] - 2*dot  (>0 by construction), key = (bits(d)&~0x7FF)|bin.
// Epilogue: fused raw-view gather + STE write + loss/fit partials.
// Partials go to per-block ARRAYS (same-address atomicAdd tails cost +5-8us:
// r9/r10/r11 evidence), reduced by a 1-block final_k.
// ---------------------------------------------------------------------------
__global__ __launch_bounds__(256, 2) void vq_main_k(
    const float* __restrict__ x, const u16* __restrict__ cbT,
    const float* __restrict__ cbnC, const float* __restrict__ cb,
    float* __restrict__ out, float* __restrict__ loss_part,
    float* __restrict__ fit_part) {
    // A: [t][k] bf16, 64x64, XOR-swizzled: elem = t*64 + (k ^ ((t&7)<<3))
    __shared__ __align__(16) u16 Ah[64 * 64];
    __shared__ float xnp[4][64];
    __shared__ float xnorm_s[64];
    __shared__ u32   kq_s[4][64];
    __shared__ int   bi_m[64];
    __shared__ float red_l[4];

    const int tid  = threadIdx.x;
    const int lane = tid & 63;
    const int bg   = tid >> 6;      // wave 0..3 = bin sub-slice
    const int col  = lane & 15;
    const int kseg = lane >> 4;     // 0..3

    const int r0 = blockIdx.x * 64;   // rows r0..r0+63; row = n*2048 + t
    const int n  = r0 >> 11;
    const int t0 = r0 & 2047;

    // ---- Stage A: x fp32 -> bf16 [t][k] swizzled; exact fp32 xnorm ----
    {
        const int t  = tid & 63;
        const int kb = tid >> 6;     // 0..3
        const float* xp = x + (size_t)n * (WIDTH * TT) + t0 + t;
        const int sw = (t & 7) << 3;
        float xs = 0.f;
#pragma unroll
        for (int it = 0; it < 8; ++it) {
            int k2 = kb * 16 + it * 2;
            float v0 = xp[(size_t)k2 * TT];
            float v1 = xp[(size_t)(k2 + 1) * TT];
            xs += v0 * v0 + v1 * v1;
            u32 pack = (u32)f2bf(v0) | ((u32)f2bf(v1) << 16);
            *(u32*)&Ah[t * 64 + (k2 ^ sw)] = pack;   // k2 even -> pair intact
        }
        xnp[kb][t] = xs;
    }
    __syncthreads();
    if (tid < 64)
        xnorm_s[tid] = xnp[0][tid] + xnp[1][tid] + xnp[2][tid] + xnp[3][tid];

    // ---- A fragments in registers (held across all 16 tiles) ----
    short8 afh[4][2];
#pragma unroll
    for (int rs = 0; rs < 4; ++rs) {
        const int rt = rs * 16 + col;
        const int sw = (rt & 7) << 3;
#pragma unroll
        for (int kc = 0; kc < 2; ++kc)
            afh[rs][kc] = *(const short8*)&Ah[rt * 64 + ((kc * 32 + kseg * 8) ^ sw)];
    }

    u32 keys[16];
#pragma unroll
    for (int i = 0; i < 16; ++i) keys[i] = 0xFFFFFFFFu;

    const int fragoff = kseg * 128 + col * 8;   // within a 1KB cbT chunk

    // Named double-buffer register sets (NO runtime indexing anywhere).
    short8 bA00, bA01, bA10, bA11, bB00, bB01, bB10, bB11;
    float  cnA0, cnA1, cnB0, cnB1;

#define PREFETCH(S00, S01, S10, S11, C0, C1, TILE) do {                       \
        const int _bb = (TILE) * 128 + bg * 32 + col;                         \
        const int _c16 = ((TILE) * 8 + bg * 2) * 1024 + fragoff;              \
        C0 = cbnC[_bb];  C1 = cbnC[_bb + 16];                                 \
        S00 = *(const short8*)&cbT[_c16];                                     \
        S01 = *(const short8*)&cbT[_c16 + 512];                               \
        S10 = *(const short8*)&cbT[_c16 + 1024];                              \
        S11 = *(const short8*)&cbT[_c16 + 1536];                              \
    } while (0)

#define COMPUTE(S00, S01, S10, S11, C0, C1, TILE) do {                        \
        const u32 bin0 = (u32)((TILE) * 128 + bg * 32 + col);                 \
        const u32 bin1 = bin0 + 16;                                           \
        _Pragma("unroll")                                                     \
        for (int rs = 0; rs < 4; ++rs) {                                      \
            f32x4 a0 = {0.f, 0.f, 0.f, 0.f}, a1 = {0.f, 0.f, 0.f, 0.f};      \
            a0 = MFMA_BF16(afh[rs][0], S00, a0, 0, 0, 0);                     \
            a0 = MFMA_BF16(afh[rs][1], S01, a0, 0, 0, 0);                     \
            a1 = MFMA_BF16(afh[rs][0], S10, a1, 0, 0, 0);                     \
            a1 = MFMA_BF16(afh[rs][1], S11, a1, 0, 0, 0);                     \
            _Pragma("unroll")                                                 \
            for (int jj = 0; jj < 4; ++jj) {                                  \
                float d0 = fmaf(-2.f, a0[jj], C0);                            \
                float d1 = fmaf(-2.f, a1[jj], C1);                            \
                u32 k0 = (__float_as_uint(d0) & KEYMASK) | bin0;              \
                u32 k1 = (__float_as_uint(d1) & KEYMASK) | bin1;              \
                u32 km = k0 < k1 ? k0 : k1;                                   \
                int li = rs * 4 + jj;                                         \
                keys[li] = km < keys[li] ? km : keys[li];                     \
            }                                                                 \
        }                                                                     \
    } while (0)

    PREFETCH(bA00, bA01, bA10, bA11, cnA0, cnA1, 0);
#pragma unroll
    for (int tp = 0; tp < 8; ++tp) {
        const int t1_ = tp * 2 + 1;
        const int t2_ = (tp * 2 + 2) & 15;     // wraps: harmless extra prefetch
        PREFETCH(bB00, bB01, bB10, bB11, cnB0, cnB1, t1_);
        COMPUTE(bA00, bA01, bA10, bA11, cnA0, cnA1, tp * 2);
        PREFETCH(bA00, bA01, bA10, bA11, cnA0, cnA1, t2_);
        COMPUTE(bB00, bB01, bB10, bB11, cnB0, cnB1, t1_);
    }
#undef PREFETCH
#undef COMPUTE

    // ---- issue epilogue x-read now (hides HBM latency under reduction) ----
    const size_t ob = (size_t)r0 * 64 + (size_t)tid * 16;
    float4 xv0 = *(const float4*)(x + ob);
    float4 xv1 = *(const float4*)(x + ob + 4);
    float4 xv2 = *(const float4*)(x + ob + 8);
    float4 xv3 = *(const float4*)(x + ob + 12);

    // ---- reduce across 16 col-lanes (u32 min = value then lowest bin) ----
#pragma unroll
    for (int m = 1; m <= 8; m <<= 1) {
#pragma unroll
        for (int i = 0; i < 16; ++i) {
            u32 ok = (u32)__shfl_xor((int)keys[i], m, 64);
            keys[i] = ok < keys[i] ? ok : keys[i];
        }
    }
    if (col == 0) {
#pragma unroll
        for (int rs = 0; rs < 4; ++rs)
#pragma unroll
            for (int jj = 0; jj < 4; ++jj)
                kq_s[bg][rs * 16 + kseg * 4 + jj] = keys[rs * 4 + jj];
    }
    __syncthreads();

    // ---- cross-wave merge + fit partial (wave 0) ----
    if (tid < 64) {
        u32 k0 = kq_s[0][tid], k1 = kq_s[1][tid];
        u32 k2 = kq_s[2][tid], k3 = kq_s[3][tid];
        u32 ka = k0 < k1 ? k0 : k1;
        u32 kb2 = k2 < k3 ? k2 : k3;
        u32 km = ka < kb2 ? ka : kb2;
        bi_m[tid] = (int)(km & 0x7FFu);
        float d = __uint_as_float(km & KEYMASK) - DBIAS;
        float fv = sqrtf(fmaxf(xnorm_s[tid] + d, 0.f));
#pragma unroll
        for (int m = 32; m >= 1; m >>= 1) fv += __shfl_xor(fv, m, 64);
        if (tid == 0) fit_part[blockIdx.x] = fv;
    }
    __syncthreads();

    // ---- fused epilogue: raw-view gather + STE write + loss partial ----
    const int rl = tid >> 2;                 // local row 0..63
    const int id = bi_m[rl];
    const float* qrow = cb + (size_t)id * 64 + (tid & 3) * 16;
    float4 q0 = *(const float4*)(qrow);
    float4 q1 = *(const float4*)(qrow + 4);
    float4 q2 = *(const float4*)(qrow + 8);
    float4 q3 = *(const float4*)(qrow + 12);
    float ls = 0.f;
#define STE(QV, XV, OFF) do {                                                 \
        float4 qo;                                                            \
        qo.x = XV.x + (QV.x - XV.x); qo.y = XV.y + (QV.y - XV.y);             \
        qo.z = XV.z + (QV.z - XV.z); qo.w = XV.w + (QV.w - XV.w);             \
        *(float4*)(out + ob + OFF) = qo;                                      \
        float dx = QV.x - XV.x, dy = QV.y - XV.y;                             \
        float dz = QV.z - XV.z, dw = QV.w - XV.w;                             \
        ls += dx * dx + dy * dy + dz * dz + dw * dw;                          \
    } while (0)
    STE(q0, xv0, 0); STE(q1, xv1, 4); STE(q2, xv2, 8); STE(q3, xv3, 12);
#undef STE
#pragma unroll
    for (int m = 32; m >= 1; m >>= 1) ls += __shfl_xor(ls, m, 64);
    if (lane == 0) red_l[bg] = ls;
    __syncthreads();
    if (tid == 0)
        loss_part[blockIdx.x] = red_l[0] + red_l[1] + red_l[2] + red_l[3];
}

// ---------------------------------------------------------------------------
// Final deterministic reduction -> loss, fit scalars
// ---------------------------------------------------------------------------
__global__ __launch_bounds__(256) void final_k(
    const float* __restrict__ loss_part, const float* __restrict__ fit_part,
    float* __restrict__ out) {
    int tid = threadIdx.x;
    float s = loss_part[tid] + loss_part[tid + 256];
    float f = fit_part[tid] + fit_part[tid + 256];
#pragma unroll
    for (int m = 32; m >= 1; m >>= 1) {
        s += __shfl_xor(s, m, 64);
        f += __shfl_xor(f, m, 64);
    }
    __shared__ float ss[4], ff[4];
    if ((tid & 63) == 0) { ss[tid >> 6] = s; ff[tid >> 6] = f; }
    __syncthreads();
    if (tid == 0) {
        float loss_sum = ss[0] + ss[1] + ss[2] + ss[3];
        float fit_sum  = ff[0] + ff[1] + ff[2] + ff[3];
        // loss = codebook_loss + 0.25*commit_loss = 1.25 * mean((q-x)^2)
        out[NELEM]     = 1.25f * loss_sum / (float)NELEM;
        out[NELEM + 1] = fit_sum / (float)NROWS;
    }
}

// ---------------------------------------------------------------------------
extern "C" void kernel_launch(void* const* d_in, const int* in_sizes, int n_in,
                              void* d_out, int out_size, void* d_ws, size_t ws_size,
                              hipStream_t stream) {
    const float* x  = (const float*)d_in[0];   // (16,64,2048) fp32
    const float* cb = (const float*)d_in[1];   // (2048,64) fp32
    float* out = (float*)d_out;                // [2097152 quantized][loss][fit]

    char* ws = (char*)d_ws;
    float* cbnC      = (float*)(ws);            // 8 KB
    u16*   cbT       = (u16*)  (ws + 8192);     // 256 KB
    float* loss_part = (float*)(ws + 270336);   // 2 KB
    float* fit_part  = (float*)(ws + 272384);   // 2 KB

    cbprep_k<<<8,        256, 0, stream>>>(cb, cbT, cbnC);
    vq_main_k<<<NBLK_VQ, 256, 0, stream>>>(x, cbT, cbnC, cb, out,
                                           loss_part, fit_part);
    final_k<<<1,         256, 0, stream>>>(loss_part, fit_part, out);
}

// Round 13
// 24.252 us; speedup vs baseline: 1.3923x; 1.0400x over previous
//
#include <hip/hip_runtime.h>
#include <math.h>

// Problem dims (fixed)
#define NN      16
#define WIDTH   64
#define TT      2048
#define NBINS   2048
#define NROWS   32768      // NN*TT
#define NELEM   2097152    // NN*WIDTH*TT
#define NBLK_VQ 512        // 64 rows per block, all 2048 bins

typedef unsigned short u16;
typedef unsigned int   u32;
typedef __attribute__((ext_vector_type(8))) short short8;   // 8 bf16 (4 VGPRs)
typedef __attribute__((ext_vector_type(4))) float f32x4;

#define MFMA_BF16 __builtin_amdgcn_mfma_f32_16x16x32_bf16
#define KEYMASK   0xFFFFF800u
// DBIAS must exceed max|2*dot(x,cb)| so the discriminant is ALWAYS > 0
// (u32 float-ordering breaks for negatives). |dot| sigma ~0.031 -> 0.5 = 16σ.
#define DBIAS     0.5f

__device__ __forceinline__ u16 f2bf(float f) {            // RNE f32 -> bf16 bits
    u32 u = __float_as_uint(f);
    u32 r = u + 0x7FFFu + ((u >> 16) & 1u);
    return (u16)(r >> 16);
}

// ---------------------------------------------------------------------------
// Prep: cbT = bf16(-2*cb) in MFMA-tiled layout (exact -2x scaling in bf16);
// cbnC = ||cb||^2 + DBIAS. 4 threads/bin (quad-shuffle norm reduce), grid 32.
// cbT chunk layout: [bin16][kc][kseg][col][8elem]; k = kc*32 + kseg*8 + i.
// With B = -2*cb and MFMA C-init = cbnC, the accumulator IS the discriminant.
// ---------------------------------------------------------------------------
__global__ __launch_bounds__(256) void cbprep_k(const float* __restrict__ cb,
                                                u16* __restrict__ cbT,
                                                float* __restrict__ cbnC) {
    int g = blockIdx.x * 256 + threadIdx.x;    // grid 32 -> 8192 threads
    int b = g >> 2, q = g & 3;                 // bin, quarter (16 k each)
    const float4* p = (const float4*)(cb + (size_t)b * 64) + q * 4;
    const int base = (b >> 4) * 1024 + (b & 15) * 8;
    float s = 0.f;
#pragma unroll
    for (int c = 0; c < 2; ++c) {              // octet o = q*2 + c
        float4 v0 = p[c * 2], v1 = p[c * 2 + 1];
        s += v0.x * v0.x + v0.y * v0.y + v0.z * v0.z + v0.w * v0.w;
        s += v1.x * v1.x + v1.y * v1.y + v1.z * v1.z + v1.w * v1.w;
        short8 h = { (short)f2bf(-2.f * v0.x), (short)f2bf(-2.f * v0.y),
                     (short)f2bf(-2.f * v0.z), (short)f2bf(-2.f * v0.w),
                     (short)f2bf(-2.f * v1.x), (short)f2bf(-2.f * v1.y),
                     (short)f2bf(-2.f * v1.z), (short)f2bf(-2.f * v1.w) };
        int o = q * 2 + c;
        *(short8*)&cbT[base + (o >> 2) * 512 + (o & 3) * 128] = h;
    }
    s += __shfl_xor(s, 1, 64);
    s += __shfl_xor(s, 2, 64);
    if (q == 0) cbnC[b] = s + DBIAS;
}

// ---------------------------------------------------------------------------
// Main: block = 64 rows x all 2048 bins. 256 threads = 4 waves, wave = bin
// slice bg (32 bins of each 128-bin tile), all 64 rows (4 MFMA row-tiles).
// B streamed from L2 via named register double-buffer (no runtime indexing,
// no barriers in the 16-tile loop). MFMA C-operand seeded with cbnC ->
// accumulator = d = cbn + DBIAS - 2*dot > 0 directly (no per-candidate fmaf).
// Argmin via sortable u32 keys: key = (bits(d)&~0x7FF)|bin.
// Epilogue: fused raw-view gather + STE write + loss/fit partials.
// Partials to per-block ARRAYS (same-address atomicAdd tails cost +5-8us:
// r9/r10/r11 evidence), reduced by a 1-block final_k.
// ---------------------------------------------------------------------------
__global__ __launch_bounds__(256, 2) void vq_main_k(
    const float* __restrict__ x, const u16* __restrict__ cbT,
    const float* __restrict__ cbnC, const float* __restrict__ cb,
    float* __restrict__ out, float* __restrict__ loss_part,
    float* __restrict__ fit_part) {
    // A: [t][k] bf16, 64x64, XOR-swizzled: elem = t*64 + (k ^ ((t&7)<<3))
    __shared__ __align__(16) u16 Ah[64 * 64];
    __shared__ float xnp[4][64];
    __shared__ float xnorm_s[64];
    __shared__ u32   kq_s[4][64];
    __shared__ int   bi_m[64];
    __shared__ float red_l[4];

    const int tid  = threadIdx.x;
    const int lane = tid & 63;
    const int bg   = tid >> 6;      // wave 0..3 = bin sub-slice
    const int col  = lane & 15;
    const int kseg = lane >> 4;     // 0..3

    const int r0 = blockIdx.x * 64;   // rows r0..r0+63; row = n*2048 + t
    const int n  = r0 >> 11;
    const int t0 = r0 & 2047;

    // ---- Stage A: x fp32 -> bf16 [t][k] swizzled; exact fp32 xnorm ----
    {
        const int t  = tid & 63;
        const int kb = tid >> 6;     // 0..3
        const float* xp = x + (size_t)n * (WIDTH * TT) + t0 + t;
        const int sw = (t & 7) << 3;
        float xs = 0.f;
#pragma unroll
        for (int it = 0; it < 8; ++it) {
            int k2 = kb * 16 + it * 2;
            float v0 = xp[(size_t)k2 * TT];
            float v1 = xp[(size_t)(k2 + 1) * TT];
            xs += v0 * v0 + v1 * v1;
            u32 pack = (u32)f2bf(v0) | ((u32)f2bf(v1) << 16);
            *(u32*)&Ah[t * 64 + (k2 ^ sw)] = pack;   // k2 even -> pair intact
        }
        xnp[kb][t] = xs;
    }
    __syncthreads();
    if (tid < 64)
        xnorm_s[tid] = xnp[0][tid] + xnp[1][tid] + xnp[2][tid] + xnp[3][tid];

    // ---- A fragments in registers (held across all 16 tiles) ----
    short8 afh[4][2];
#pragma unroll
    for (int rs = 0; rs < 4; ++rs) {
        const int rt = rs * 16 + col;
        const int sw = (rt & 7) << 3;
#pragma unroll
        for (int kc = 0; kc < 2; ++kc)
            afh[rs][kc] = *(const short8*)&Ah[rt * 64 + ((kc * 32 + kseg * 8) ^ sw)];
    }

    u32 keys[16];
#pragma unroll
    for (int i = 0; i < 16; ++i) keys[i] = 0xFFFFFFFFu;

    const int fragoff = kseg * 128 + col * 8;   // within a 1KB cbT chunk

    // Named double-buffer register sets (NO runtime indexing anywhere).
    short8 bA00, bA01, bA10, bA11, bB00, bB01, bB10, bB11;
    float  cnA0, cnA1, cnB0, cnB1;

#define PREFETCH(S00, S01, S10, S11, C0, C1, TILE) do {                       \
        const int _bb = (TILE) * 128 + bg * 32 + col;                         \
        const int _c16 = ((TILE) * 8 + bg * 2) * 1024 + fragoff;              \
        C0 = cbnC[_bb];  C1 = cbnC[_bb + 16];                                 \
        S00 = *(const short8*)&cbT[_c16];                                     \
        S01 = *(const short8*)&cbT[_c16 + 512];                               \
        S10 = *(const short8*)&cbT[_c16 + 1024];                              \
        S11 = *(const short8*)&cbT[_c16 + 1536];                              \
    } while (0)

#define COMPUTE(S00, S01, S10, S11, C0, C1, TILE) do {                        \
        const u32 bin0 = (u32)((TILE) * 128 + bg * 32 + col);                 \
        const u32 bin1 = bin0 + 16;                                           \
        const f32x4 ci0 = {C0, C0, C0, C0};                                   \
        const f32x4 ci1 = {C1, C1, C1, C1};                                   \
        _Pragma("unroll")                                                     \
        for (int rs = 0; rs < 4; ++rs) {                                      \
            f32x4 a0 = MFMA_BF16(afh[rs][0], S00, ci0, 0, 0, 0);              \
            a0 = MFMA_BF16(afh[rs][1], S01, a0, 0, 0, 0);                     \
            f32x4 a1 = MFMA_BF16(afh[rs][0], S10, ci1, 0, 0, 0);              \
            a1 = MFMA_BF16(afh[rs][1], S11, a1, 0, 0, 0);                     \
            _Pragma("unroll")                                                 \
            for (int jj = 0; jj < 4; ++jj) {                                  \
                u32 k0 = (__float_as_uint(a0[jj]) & KEYMASK) | bin0;          \
                u32 k1 = (__float_as_uint(a1[jj]) & KEYMASK) | bin1;          \
                u32 km = k0 < k1 ? k0 : k1;                                   \
                int li = rs * 4 + jj;                                         \
                keys[li] = km < keys[li] ? km : keys[li];                     \
            }                                                                 \
        }                                                                     \
    } while (0)

    PREFETCH(bA00, bA01, bA10, bA11, cnA0, cnA1, 0);
#pragma unroll
    for (int tp = 0; tp < 8; ++tp) {
        const int t1_ = tp * 2 + 1;
        const int t2_ = (tp * 2 + 2) & 15;     // wraps: harmless extra prefetch
        PREFETCH(bB00, bB01, bB10, bB11, cnB0, cnB1, t1_);
        COMPUTE(bA00, bA01, bA10, bA11, cnA0, cnA1, tp * 2);
        PREFETCH(bA00, bA01, bA10, bA11, cnA0, cnA1, t2_);
        COMPUTE(bB00, bB01, bB10, bB11, cnB0, cnB1, t1_);
    }
#undef PREFETCH
#undef COMPUTE

    // ---- issue epilogue x-read now (hides HBM latency under reduction) ----
    const size_t ob = (size_t)r0 * 64 + (size_t)tid * 16;
    float4 xv0 = *(const float4*)(x + ob);
    float4 xv1 = *(const float4*)(x + ob + 4);
    float4 xv2 = *(const float4*)(x + ob + 8);
    float4 xv3 = *(const float4*)(x + ob + 12);

    // ---- reduce across 16 col-lanes (u32 min = value then lowest bin) ----
#pragma unroll
    for (int m = 1; m <= 8; m <<= 1) {
#pragma unroll
        for (int i = 0; i < 16; ++i) {
            u32 ok = (u32)__shfl_xor((int)keys[i], m, 64);
            keys[i] = ok < keys[i] ? ok : keys[i];
        }
    }
    if (col == 0) {
#pragma unroll
        for (int rs = 0; rs < 4; ++rs)
#pragma unroll
            for (int jj = 0; jj < 4; ++jj)
                kq_s[bg][rs * 16 + kseg * 4 + jj] = keys[rs * 4 + jj];
    }
    __syncthreads();

    // ---- cross-wave merge + fit partial (wave 0) ----
    if (tid < 64) {
        u32 k0 = kq_s[0][tid], k1 = kq_s[1][tid];
        u32 k2 = kq_s[2][tid], k3 = kq_s[3][tid];
        u32 ka = k0 < k1 ? k0 : k1;
        u32 kb2 = k2 < k3 ? k2 : k3;
        u32 km = ka < kb2 ? ka : kb2;
        bi_m[tid] = (int)(km & 0x7FFu);
        float d = __uint_as_float(km & KEYMASK) - DBIAS;
        float fv = sqrtf(fmaxf(xnorm_s[tid] + d, 0.f));
#pragma unroll
        for (int m = 32; m >= 1; m >>= 1) fv += __shfl_xor(fv, m, 64);
        if (tid == 0) fit_part[blockIdx.x] = fv;
    }
    __syncthreads();

    // ---- fused epilogue: raw-view gather + STE write + loss partial ----
    const int rl = tid >> 2;                 // local row 0..63
    const int id = bi_m[rl];
    const float* qrow = cb + (size_t)id * 64 + (tid & 3) * 16;
    float4 q0 = *(const float4*)(qrow);
    float4 q1 = *(const float4*)(qrow + 4);
    float4 q2 = *(const float4*)(qrow + 8);
    float4 q3 = *(const float4*)(qrow + 12);
    float ls = 0.f;
#define STE(QV, XV, OFF) do {                                                 \
        float4 qo;                                                            \
        qo.x = XV.x + (QV.x - XV.x); qo.y = XV.y + (QV.y - XV.y);             \
        qo.z = XV.z + (QV.z - XV.z); qo.w = XV.w + (QV.w - XV.w);             \
        *(float4*)(out + ob + OFF) = qo;                                      \
        float dx = QV.x - XV.x, dy = QV.y - XV.y;                             \
        float dz = QV.z - XV.z, dw = QV.w - XV.w;                             \
        ls += dx * dx + dy * dy + dz * dz + dw * dw;                          \
    } while (0)
    STE(q0, xv0, 0); STE(q1, xv1, 4); STE(q2, xv2, 8); STE(q3, xv3, 12);
#undef STE
#pragma unroll
    for (int m = 32; m >= 1; m >>= 1) ls += __shfl_xor(ls, m, 64);
    if (lane == 0) red_l[bg] = ls;
    __syncthreads();
    if (tid == 0)
        loss_part[blockIdx.x] = red_l[0] + red_l[1] + red_l[2] + red_l[3];
}

// ---------------------------------------------------------------------------
// Final deterministic reduction -> loss, fit scalars
// ---------------------------------------------------------------------------
__global__ __launch_bounds__(256) void final_k(
    const float* __restrict__ loss_part, const float* __restrict__ fit_part,
    float* __restrict__ out) {
    int tid = threadIdx.x;
    float s = loss_part[tid] + loss_part[tid + 256];
    float f = fit_part[tid] + fit_part[tid + 256];
#pragma unroll
    for (int m = 32; m >= 1; m >>= 1) {
        s += __shfl_xor(s, m, 64);
        f += __shfl_xor(f, m, 64);
    }
    __shared__ float ss[4], ff[4];
    if ((tid & 63) == 0) { ss[tid >> 6] = s; ff[tid >> 6] = f; }
    __syncthreads();
    if (tid == 0) {
        float loss_sum = ss[0] + ss[1] + ss[2] + ss[3];
        float fit_sum  = ff[0] + ff[1] + ff[2] + ff[3];
        // loss = codebook_loss + 0.25*commit_loss = 1.25 * mean((q-x)^2)
        out[NELEM]     = 1.25f * loss_sum / (float)NELEM;
        out[NELEM + 1] = fit_sum / (float)NROWS;
    }
}

// ---------------------------------------------------------------------------
extern "C" void kernel_launch(void* const* d_in, const int* in_sizes, int n_in,
                              void* d_out, int out_size, void* d_ws, size_t ws_size,
                              hipStream_t stream) {
    const float* x  = (const float*)d_in[0];   // (16,64,2048) fp32
    const float* cb = (const float*)d_in[1];   // (2048,64) fp32
    float* out = (float*)d_out;                // [2097152 quantized][loss][fit]

    char* ws = (char*)d_ws;
    float* cbnC      = (float*)(ws);            // 8 KB
    u16*   cbT       = (u16*)  (ws + 8192);     // 256 KB
    float* loss_part = (float*)(ws + 270336);   // 2 KB
    float* fit_part  = (float*)(ws + 272384);   // 2 KB

    cbprep_k<<<32,       256, 0, stream>>>(cb, cbT, cbnC);
    vq_main_k<<<NBLK_VQ, 256, 0, stream>>>(x, cbT, cbnC, cb, out,
                                           loss_part, fit_part);
    final_k<<<1,         256, 0, stream>>>(loss_part, fit_part, out);
}